// Round 4
// baseline (990.856 us; speedup 1.0000x reference)
//
#include <hip/hip_runtime.h>

typedef __attribute__((ext_vector_type(8))) short bf16x8_t;
typedef __attribute__((ext_vector_type(4))) float f32x4_t;

#define BATCH 4
#define CH 64
#define HIN 256
#define WIN 512
#define NDISP 65
#define TY 4
#define TX 254

// main-kernel LDS byte offsets
#define X0_OFF 0
#define X0_PS 8192               // per-parity x0 staging (128 lines x 64B)
#define X1_OFF 16384
#define X1_PS 12288              // per-parity x1 staging (192 lines x 64B)
#define QB_OFF 40960             // float[17][257] Q chunk = 17476 B
#define S0X_OFF 58448            // float[256]
#define L0X_OFF 59472            // float[256]
#define S1X_OFF 60496            // float[384]
#define L1X_OFF 62032            // float[384]
#define SMEM_BYTES 63568         // < 80 KB -> 2 blocks/CU

// workspace float offsets
#define CS0_OFF 0
#define CQ0_OFF  524288
#define CS1_OFF 1048576
#define CQ1_OFF 1572864
#define SB0_OFF 2097152
#define LB0_OFF 2621440
#define SB1_OFF 3145728          // [B][H][648], i = v+66, v in [-66,581]
#define LB1_OFF 3809280

// ---------------- pass A: per-(b,y) channel column sums ----------------
__global__ __launch_bounds__(512)
void colsum_kernel(const float* __restrict__ x0, const float* __restrict__ x1,
                   float* __restrict__ ws) {
  const int y = blockIdx.x, b = blockIdx.y, x = threadIdx.x;
  const size_t plane = (size_t)HIN * WIN;
  const float* p0 = x0 + (size_t)b * CH * plane + (size_t)y * WIN + x;
  const float* p1 = x1 + (size_t)b * CH * plane + (size_t)y * WIN + x;
  float s0 = 0.f, q0 = 0.f, s1 = 0.f, q1 = 0.f;
#pragma unroll 8
  for (int c = 0; c < CH; ++c) {
    const float v = p0[c * plane];
    const float w = p1[c * plane];
    s0 += v; q0 += v * v;
    s1 += w; q1 += w * w;
  }
  const size_t o = ((size_t)b * HIN + y) * WIN + x;
  ws[CS0_OFF + o] = s0; ws[CQ0_OFF + o] = q0;
  ws[CS1_OFF + o] = s1; ws[CQ1_OFF + o] = q1;
}

// ---------------- pass B: 3x3 boxed patch stats + norms ----------------
__global__ __launch_bounds__(512)
void boxnorm_kernel(float* __restrict__ ws) {
  const int y = blockIdx.x, b = blockIdx.y;
  const int tid = threadIdx.x;
  const float invn = 1.f / 576.f;
  const int ylo = (y > 0) ? y - 1 : 0;
  const int yhi = (y < HIN - 1) ? y + 1 : HIN - 1;
  // x0 side: one x per thread
  {
    const int x = tid;
    float s = 0.f, q = 0.f;
    for (int yy = ylo; yy <= yhi; ++yy) {
      const float* rs = ws + CS0_OFF + ((size_t)b * HIN + yy) * WIN;
      const float* rq = ws + CQ0_OFF + ((size_t)b * HIN + yy) * WIN;
      const int xlo = (x > 0) ? x - 1 : 0;
      const int xhi = (x < WIN - 1) ? x + 1 : WIN - 1;
      for (int xx = xlo; xx <= xhi; ++xx) { s += rs[xx]; q += rq[xx]; }
    }
    const size_t o = ((size_t)b * HIN + y) * WIN + x;
    ws[SB0_OFF + o] = s;
    ws[LB0_OFF + o] = sqrtf(fmaxf(q - s * s * invn, 0.f));
  }
  // x1 side: extended v range, i = v+66, v in [-66,581]
  for (int i = tid; i < 648; i += 512) {
    const int v = i - 66;
    float s = 0.f, q = 0.f;
    const int xlo = (v - 1 > 0) ? v - 1 : 0;
    const int xhi = (v + 1 < WIN - 1) ? v + 1 : WIN - 1;
    if (v + 1 >= 0 && v - 1 < WIN) {
      for (int yy = ylo; yy <= yhi; ++yy) {
        const float* rs = ws + CS1_OFF + ((size_t)b * HIN + yy) * WIN;
        const float* rq = ws + CQ1_OFF + ((size_t)b * HIN + yy) * WIN;
        for (int xx = xlo; xx <= xhi; ++xx) { s += rs[xx]; q += rq[xx]; }
      }
    }
    const size_t o = ((size_t)b * HIN + y) * 648 + i;
    ws[SB1_OFF + o] = s;
    ws[LB1_OFF + o] = sqrtf(fmaxf(q - s * s * invn, 0.f));
  }
}

// ---------------- main: banded MFMA cost volume ----------------
__global__ __launch_bounds__(512, 4)
void corrzn_kernel(const float* __restrict__ x0, const float* __restrict__ x1,
                   const float* __restrict__ ws, float* __restrict__ out) {
  __shared__ __align__(16) char smem[SMEM_BYTES];

  const int tid  = threadIdx.x;
  const int lane = tid & 63;
  const int wv   = tid >> 6;      // 0..7
  const int p    = wv & 1;        // parity this wave works on
  const int jj   = wv >> 1;       // 0..3
  const int chunk0 = 2 * jj;      // wave's M-chunks: chunk0, chunk0+1
  const int lm = lane & 15;
  const int lk = lane >> 4;

  const int x0blk = blockIdx.x * TX;       // 0, 254, 508
  const int y0    = blockIdx.y * TY;       // output row base
  const int b     = blockIdx.z;

  const size_t plane = (size_t)HIN * WIN;
  const float* x0b = x0 + (size_t)b * CH * plane;
  const float* x1b = x1 + (size_t)b * CH * plane;

  f32x4_t acc[TY][2][5];
#pragma unroll
  for (int t = 0; t < TY; ++t)
#pragma unroll
    for (int mc = 0; mc < 2; ++mc)
#pragma unroll
      for (int T = 0; T < 5; ++T)
        acc[t][mc][T] = (f32x4_t){0.f, 0.f, 0.f, 0.f};

  // ================= K-loop: 6 padded rows x 2 channel chunks =================
  for (int k = 0; k < 12; ++k) {
    const int r = k >> 1, cc = k & 1;
    const int orow = y0 + r - 1;
    const bool rowok = (orow >= 0) && (orow < HIN);

    __syncthreads();               // readers of previous tile done
    if (rowok) {
      // stage row r, channels cc*32..+31 as bf16, parity-split, swizzled
#pragma unroll
      for (int it = 0; it < 10; ++it) {
        const int s = it * 512 + tid;
        int cl, wp, isx1;
        if (it < 4) { cl = 2 * (s >> 7); wp = s & 127; isx1 = 0; }
        else { const int s2 = s - 2048; const int cp2 = s2 / 192; cl = 2 * cp2; wp = s2 - 192 * cp2; isx1 = 1; }
        const int w0 = (isx1 ? x0blk - 65 : x0blk - 1) + 2 * wp;
        float v00 = 0.f, v01 = 0.f, v10 = 0.f, v11 = 0.f;
        const float* src = (isx1 ? x1b : x0b) + (size_t)(cc * 32 + cl) * plane + (size_t)orow * WIN;
        if (w0 >= 0 && w0 < WIN)         { v00 = src[w0];     v10 = src[plane + w0]; }
        if (w0 + 1 >= 0 && w0 + 1 < WIN) { v01 = src[w0 + 1]; v11 = src[plane + w0 + 1]; }
        unsigned pk0, pk1;
        asm("v_cvt_pk_bf16_f32 %0, %1, %2" : "=v"(pk0) : "v"(v00), "v"(v10));
        asm("v_cvt_pk_bf16_f32 %0, %1, %2" : "=v"(pk1) : "v"(v01), "v"(v11));
        const int slot = (cl >> 3) ^ ((wp >> 1) & 3);
        const int boff = (isx1 ? X1_OFF : X0_OFF) + wp * 64 + slot * 16 + (cl & 7) * 2;
        const int ps = isx1 ? X1_PS : X0_PS;
        *(unsigned*)(smem + boff)      = pk0;   // parity 0 (rel even)
        *(unsigned*)(smem + boff + ps) = pk1;   // parity 1 (rel odd)
      }
    }
    __syncthreads();               // tile ready
    if (rowok) {
      bf16x8_t afr[2], bfr[6];
#pragma unroll
      for (int mc = 0; mc < 2; ++mc) {
        const int pos = 16 * (chunk0 + mc) + lm;
        const int slot = lk ^ ((pos >> 1) & 3);
        afr[mc] = *(const bf16x8_t*)(smem + X0_OFF + p * X0_PS + pos * 64 + slot * 16);
      }
#pragma unroll
      for (int u = 0; u < 6; ++u) {
        const int pos = 16 * (chunk0 + u) + lm;
        const int slot = lk ^ ((pos >> 1) & 3);
        bfr[u] = *(const bf16x8_t*)(smem + X1_OFF + p * X1_PS + pos * 64 + slot * 16);
      }
#pragma unroll
      for (int t = 0; t < TY; ++t) {
        if (t >= r - 2 && t <= r) {
#pragma unroll
          for (int mc = 0; mc < 2; ++mc)
#pragma unroll
            for (int T = 0; T < 5; ++T)
              acc[t][mc][T] = __builtin_amdgcn_mfma_f32_16x16x32_bf16(
                  afr[mc], bfr[mc + T], acc[t][mc][T], 0, 0, 0);
        }
      }
    }
  }

  // ================= epilogue: 4 rows x 4 di-chunks =================
  float* Qc  = (float*)(smem + QB_OFF);
  float* s0x = (float*)(smem + S0X_OFF);
  float* l0x = (float*)(smem + L0X_OFF);
  float* s1x = (float*)(smem + S1X_OFF);
  float* l1x = (float*)(smem + L1X_OFF);
  const float invn = 1.f / 576.f;

#pragma unroll
  for (int t = 0; t < TY; ++t) {
    const int row = y0 + t;
    __syncthreads();   // previous t's readers done before overwriting aux rows
    for (int i = tid; i < 254; i += 512) {
      const int x = x0blk + i;
      const size_t o = ((size_t)b * HIN + row) * WIN + x;
      s0x[i] = (x < WIN) ? ws[SB0_OFF + o] : 0.f;
      l0x[i] = (x < WIN) ? ws[LB0_OFF + o] : 0.f;
    }
    for (int j2 = tid; j2 < 382; j2 += 512) {
      const int idx = x0blk + 2 + j2;            // = (v = x0blk-64+j2) + 66
      const size_t o = ((size_t)b * HIN + row) * 648 + idx;
      s1x[j2] = (idx < 648) ? ws[SB1_OFF + o] : 0.f;
      l1x[j2] = (idx < 648) ? ws[LB1_OFF + o] : 0.f;
    }
    for (int c = 0; c < 4; ++c) {
      const int c0 = 17 * c;
      const int nd = (c == 3) ? 14 : 17;
      __syncthreads();   // aux visible (c=0) / previous chunk's reads done
      // dump this chunk's diagonals
#pragma unroll
      for (int mc = 0; mc < 2; ++mc) {
        const int m0 = 16 * (chunk0 + mc);
#pragma unroll
        for (int T = 0; T < 5; ++T) {
          const int n0 = 16 * (chunk0 + mc + T);
#pragma unroll
          for (int q = 0; q < 4; ++q) {
            const int mg = m0 + lk * 4 + q;
            const int di = (n0 + lm) - mg;
            if (di >= c0 && di < c0 + nd)
              Qc[(di - c0) * 257 + 2 * mg + p] = acc[t][mc][T][q];
          }
        }
      }
      __syncthreads();
      const int tot = nd * TX;
      for (int oi = tid; oi < tot; oi += 512) {
        const int dic = oi / TX;
        const int xl = oi - dic * TX;
        const int x = x0blk + xl;
        if (x < WIN) {
          const int di = c0 + dic;
          const float q3 = Qc[dic * 257 + xl] + Qc[dic * 257 + xl + 1] + Qc[dic * 257 + xl + 2];
          const int j = xl + 2 * di;             // v-local index
          const float numer = q3 - s0x[xl] * s1x[j] * invn;
          const float den = l0x[xl] * l1x[j] + 1e-8f;
          out[(((size_t)b * NDISP + di) * HIN + row) * WIN + x] = numer / den;
        }
      }
    }
  }
}

extern "C" void kernel_launch(void* const* d_in, const int* in_sizes, int n_in,
                              void* d_out, int out_size, void* d_ws, size_t ws_size,
                              hipStream_t stream) {
  const float* x0 = (const float*)d_in[0];
  const float* x1 = (const float*)d_in[1];
  float* out = (float*)d_out;
  float* wsf = (float*)d_ws;

  colsum_kernel<<<dim3(HIN, BATCH), 512, 0, stream>>>(x0, x1, wsf);
  boxnorm_kernel<<<dim3(HIN, BATCH), 512, 0, stream>>>(wsf);
  corrzn_kernel<<<dim3(3, HIN / TY, BATCH), 512, 0, stream>>>(x0, x1, wsf, out);
}

// Round 5
// 410.508 us; speedup vs baseline: 2.4137x; 2.4137x over previous
//
#include <hip/hip_runtime.h>

typedef __attribute__((ext_vector_type(8))) short bf16x8_t;
typedef __attribute__((ext_vector_type(4))) float f32x4_t;

#define BATCH 4
#define CH 64
#define HIN 256
#define WIN 512
#define NDISP 65
#define TY 4
#define TX 254

// main-kernel LDS byte offsets
#define X0_OFF 0
#define X0_PS 8192               // per-parity x0 staging (128 lines x 64B)
#define X1_OFF 16384
#define X1_PS 12288              // per-parity x1 staging (192 lines x 64B)
#define QB_OFF 40960             // float[17][257] Q chunk = 17476 B
#define S0X_OFF 58448            // float[256]
#define L0X_OFF 59472            // float[256]
#define S1X_OFF 60496            // float[384]
#define L1X_OFF 62032            // float[384]
#define SMEM_BYTES 63568         // < 80 KB -> 2 blocks/CU

// workspace float offsets
#define CS0_OFF 0
#define CQ0_OFF  524288
#define CS1_OFF 1048576
#define CQ1_OFF 1572864
#define SB0_OFF 2097152
#define LB0_OFF 2621440
#define SB1_OFF 3145728          // [B][H][648], i = v+66, v in [-66,581]
#define LB1_OFF 3809280

// ---------------- pass A: per-(b,y) channel column sums ----------------
__global__ __launch_bounds__(512)
void colsum_kernel(const float* __restrict__ x0, const float* __restrict__ x1,
                   float* __restrict__ ws) {
  const int y = blockIdx.x, b = blockIdx.y, x = threadIdx.x;
  const size_t plane = (size_t)HIN * WIN;
  const float* p0 = x0 + (size_t)b * CH * plane + (size_t)y * WIN + x;
  const float* p1 = x1 + (size_t)b * CH * plane + (size_t)y * WIN + x;
  float s0 = 0.f, q0 = 0.f, s1 = 0.f, q1 = 0.f;
#pragma unroll 8
  for (int c = 0; c < CH; ++c) {
    const float v = p0[c * plane];
    const float w = p1[c * plane];
    s0 += v; q0 += v * v;
    s1 += w; q1 += w * w;
  }
  const size_t o = ((size_t)b * HIN + y) * WIN + x;
  ws[CS0_OFF + o] = s0; ws[CQ0_OFF + o] = q0;
  ws[CS1_OFF + o] = s1; ws[CQ1_OFF + o] = q1;
}

// ---------------- pass B: 3x3 boxed patch stats + norms ----------------
__global__ __launch_bounds__(512)
void boxnorm_kernel(float* __restrict__ ws) {
  const int y = blockIdx.x, b = blockIdx.y;
  const int tid = threadIdx.x;
  const float invn = 1.f / 576.f;
  const int ylo = (y > 0) ? y - 1 : 0;
  const int yhi = (y < HIN - 1) ? y + 1 : HIN - 1;
  // x0 side: one x per thread
  {
    const int x = tid;
    float s = 0.f, q = 0.f;
    for (int yy = ylo; yy <= yhi; ++yy) {
      const float* rs = ws + CS0_OFF + ((size_t)b * HIN + yy) * WIN;
      const float* rq = ws + CQ0_OFF + ((size_t)b * HIN + yy) * WIN;
      const int xlo = (x > 0) ? x - 1 : 0;
      const int xhi = (x < WIN - 1) ? x + 1 : WIN - 1;
      for (int xx = xlo; xx <= xhi; ++xx) { s += rs[xx]; q += rq[xx]; }
    }
    const size_t o = ((size_t)b * HIN + y) * WIN + x;
    ws[SB0_OFF + o] = s;
    ws[LB0_OFF + o] = sqrtf(fmaxf(q - s * s * invn, 0.f));
  }
  // x1 side: extended v range, i = v+66, v in [-66,581]
  for (int i = tid; i < 648; i += 512) {
    const int v = i - 66;
    float s = 0.f, q = 0.f;
    const int xlo = (v - 1 > 0) ? v - 1 : 0;
    const int xhi = (v + 1 < WIN - 1) ? v + 1 : WIN - 1;
    if (v + 1 >= 0 && v - 1 < WIN) {
      for (int yy = ylo; yy <= yhi; ++yy) {
        const float* rs = ws + CS1_OFF + ((size_t)b * HIN + yy) * WIN;
        const float* rq = ws + CQ1_OFF + ((size_t)b * HIN + yy) * WIN;
        for (int xx = xlo; xx <= xhi; ++xx) { s += rs[xx]; q += rq[xx]; }
      }
    }
    const size_t o = ((size_t)b * HIN + y) * 648 + i;
    ws[SB1_OFF + o] = s;
    ws[LB1_OFF + o] = sqrtf(fmaxf(q - s * s * invn, 0.f));
  }
}

// ---------------- main: banded MFMA cost volume ----------------
__global__ __launch_bounds__(512, 2)
void corrzn_kernel(const float* __restrict__ x0, const float* __restrict__ x1,
                   const float* __restrict__ ws, float* __restrict__ out) {
  __shared__ __align__(16) char smem[SMEM_BYTES];

  const int tid  = threadIdx.x;
  const int lane = tid & 63;
  const int wv   = tid >> 6;      // 0..7
  const int p    = wv & 1;        // parity this wave works on
  const int jj   = wv >> 1;       // 0..3
  const int chunk0 = 2 * jj;      // wave's M-chunks: chunk0, chunk0+1
  const int lm = lane & 15;
  const int lk = lane >> 4;

  const int x0blk = blockIdx.x * TX;       // 0, 254, 508
  const int y0    = blockIdx.y * TY;       // output row base
  const int b     = blockIdx.z;

  const size_t plane = (size_t)HIN * WIN;
  const float* x0b = x0 + (size_t)b * CH * plane;
  const float* x1b = x1 + (size_t)b * CH * plane;

  f32x4_t acc[TY][2][5];
#pragma unroll
  for (int t = 0; t < TY; ++t)
#pragma unroll
    for (int mc = 0; mc < 2; ++mc)
#pragma unroll
      for (int T = 0; T < 5; ++T)
        acc[t][mc][T] = (f32x4_t){0.f, 0.f, 0.f, 0.f};

  // ================= K-loop: 6 padded rows x 2 channel chunks =================
  for (int k = 0; k < 12; ++k) {
    const int r = k >> 1, cc = k & 1;
    const int orow = y0 + r - 1;
    const bool rowok = (orow >= 0) && (orow < HIN);

    __syncthreads();               // readers of previous tile done
    if (rowok) {
      // stage row r, channels cc*32..+31 as bf16, parity-split, swizzled.
      // thread->(cp,wp) map: per wave 4 channel-pairs x 16 positions ->
      // LDS write banks fully spread (2-way, free) and 4x128B load segments.
#pragma unroll
      for (int it = 0; it < 10; ++it) {
        const int s = it * 512 + tid;
        int cp, wp, isx1;
        if (it < 4) {                    // x0: s in [0,2048)
          const int h = s >> 6;          // 0..31
          wp = (s & 15) + 16 * (h >> 2); // 0..127
          cp = ((s >> 4) & 3) + 4 * (h & 3);
          isx1 = 0;
        } else {                         // x1: s2 in [0,3072)
          const int s2 = s - 2048;
          const int h = s2 >> 6;         // 0..47
          wp = (s2 & 15) + 16 * (h >> 2);// 0..191
          cp = ((s2 >> 4) & 3) + 4 * (h & 3);
          isx1 = 1;
        }
        const int cl = 2 * cp;
        const int w0 = (isx1 ? x0blk - 65 : x0blk - 1) + 2 * wp;
        float v00 = 0.f, v01 = 0.f, v10 = 0.f, v11 = 0.f;
        const float* src = (isx1 ? x1b : x0b) + (size_t)(cc * 32 + cl) * plane + (size_t)orow * WIN;
        if (w0 >= 0 && w0 < WIN)         { v00 = src[w0];     v10 = src[plane + w0]; }
        if (w0 + 1 >= 0 && w0 + 1 < WIN) { v01 = src[w0 + 1]; v11 = src[plane + w0 + 1]; }
        unsigned pk0, pk1;
        asm("v_cvt_pk_bf16_f32 %0, %1, %2" : "=v"(pk0) : "v"(v00), "v"(v10));
        asm("v_cvt_pk_bf16_f32 %0, %1, %2" : "=v"(pk1) : "v"(v01), "v"(v11));
        const int slot = (cp >> 2) ^ ((wp >> 1) & 3);
        const int boff = (isx1 ? X1_OFF : X0_OFF) + wp * 64 + slot * 16 + (cp & 3) * 4;
        const int ps = isx1 ? X1_PS : X0_PS;
        *(unsigned*)(smem + boff)      = pk0;   // parity 0 (rel even)
        *(unsigned*)(smem + boff + ps) = pk1;   // parity 1 (rel odd)
      }
    }
    __syncthreads();               // tile ready
    if (rowok) {
      bf16x8_t afr[2], bfr[6];
#pragma unroll
      for (int mc = 0; mc < 2; ++mc) {
        const int pos = 16 * (chunk0 + mc) + lm;
        const int slot = lk ^ ((pos >> 1) & 3);
        afr[mc] = *(const bf16x8_t*)(smem + X0_OFF + p * X0_PS + pos * 64 + slot * 16);
      }
#pragma unroll
      for (int u = 0; u < 6; ++u) {
        const int pos = 16 * (chunk0 + u) + lm;
        const int slot = lk ^ ((pos >> 1) & 3);
        bfr[u] = *(const bf16x8_t*)(smem + X1_OFF + p * X1_PS + pos * 64 + slot * 16);
      }
#pragma unroll
      for (int t = 0; t < TY; ++t) {
        if (t >= r - 2 && t <= r) {
#pragma unroll
          for (int mc = 0; mc < 2; ++mc)
#pragma unroll
            for (int T = 0; T < 5; ++T)
              acc[t][mc][T] = __builtin_amdgcn_mfma_f32_16x16x32_bf16(
                  afr[mc], bfr[mc + T], acc[t][mc][T], 0, 0, 0);
        }
      }
    }
  }

  // ================= epilogue: 4 rows x 4 di-chunks =================
  float* Qc  = (float*)(smem + QB_OFF);
  float* s0x = (float*)(smem + S0X_OFF);
  float* l0x = (float*)(smem + L0X_OFF);
  float* s1x = (float*)(smem + S1X_OFF);
  float* l1x = (float*)(smem + L1X_OFF);
  const float invn = 1.f / 576.f;

#pragma unroll
  for (int t = 0; t < TY; ++t) {
    const int row = y0 + t;
    __syncthreads();   // previous t's readers done before overwriting aux rows
    for (int i = tid; i < 254; i += 512) {
      const int x = x0blk + i;
      const size_t o = ((size_t)b * HIN + row) * WIN + x;
      s0x[i] = (x < WIN) ? ws[SB0_OFF + o] : 0.f;
      l0x[i] = (x < WIN) ? ws[LB0_OFF + o] : 0.f;
    }
    for (int j2 = tid; j2 < 382; j2 += 512) {
      const int idx = x0blk + 2 + j2;            // = (v = x0blk-64+j2) + 66
      const size_t o = ((size_t)b * HIN + row) * 648 + idx;
      s1x[j2] = (idx < 648) ? ws[SB1_OFF + o] : 0.f;
      l1x[j2] = (idx < 648) ? ws[LB1_OFF + o] : 0.f;
    }
    for (int c = 0; c < 4; ++c) {
      const int c0 = 17 * c;
      const int nd = (c == 3) ? 14 : 17;
      __syncthreads();   // aux visible (c=0) / previous chunk's reads done
      // dump this chunk's diagonals
#pragma unroll
      for (int mc = 0; mc < 2; ++mc) {
        const int m0 = 16 * (chunk0 + mc);
#pragma unroll
        for (int T = 0; T < 5; ++T) {
          const int n0 = 16 * (chunk0 + mc + T);
#pragma unroll
          for (int q = 0; q < 4; ++q) {
            const int mg = m0 + lk * 4 + q;
            const int di = (n0 + lm) - mg;
            if (di >= c0 && di < c0 + nd)
              Qc[(di - c0) * 257 + 2 * mg + p] = acc[t][mc][T][q];
          }
        }
      }
      __syncthreads();
      const int tot = nd * TX;
      for (int oi = tid; oi < tot; oi += 512) {
        const int dic = oi / TX;
        const int xl = oi - dic * TX;
        const int x = x0blk + xl;
        if (x < WIN) {
          const int di = c0 + dic;
          const float q3 = Qc[dic * 257 + xl] + Qc[dic * 257 + xl + 1] + Qc[dic * 257 + xl + 2];
          const int j = xl + 2 * di;             // v-local index
          const float numer = q3 - s0x[xl] * s1x[j] * invn;
          const float den = l0x[xl] * l1x[j] + 1e-8f;
          out[(((size_t)b * NDISP + di) * HIN + row) * WIN + x] = numer / den;
        }
      }
    }
  }
}

extern "C" void kernel_launch(void* const* d_in, const int* in_sizes, int n_in,
                              void* d_out, int out_size, void* d_ws, size_t ws_size,
                              hipStream_t stream) {
  const float* x0 = (const float*)d_in[0];
  const float* x1 = (const float*)d_in[1];
  float* out = (float*)d_out;
  float* wsf = (float*)d_ws;

  colsum_kernel<<<dim3(HIN, BATCH), 512, 0, stream>>>(x0, x1, wsf);
  boxnorm_kernel<<<dim3(HIN, BATCH), 512, 0, stream>>>(wsf);
  corrzn_kernel<<<dim3(3, HIN / TY, BATCH), 512, 0, stream>>>(x0, x1, wsf, out);
}